// Round 5
// baseline (151.485 us; speedup 1.0000x reference)
//
#include <hip/hip_runtime.h>
#include <hip/hip_fp16.h>

#define LDIM 256
#define NDIM 256
#define DZC  128
#define HN   4
#define DHD  32
#define DCC  128
#define MROWS (LDIM*NDIM)

typedef _Float16 f16;
typedef _Float16 f16x4 __attribute__((ext_vector_type(4)));
typedef _Float16 f16x8 __attribute__((ext_vector_type(8)));
typedef float    f32x4 __attribute__((ext_vector_type(4)));

#define SCAL 0.17677669529663687f   // 1/sqrt(32)

// ---------------- K0b: pack W^T f16 — w16[p][col][k] = W_p[k][col] ----------------
__global__ __launch_bounds__(256) void k0b_pack(
    const float* __restrict__ Wq, const float* __restrict__ Wk,
    const float* __restrict__ Wv, const float* __restrict__ Wg,
    const float* __restrict__ Wo, f16* __restrict__ w16)
{
  const float* Ws[5] = {Wq, Wk, Wv, Wg, Wo};
  const int tid = blockIdx.x * 256 + threadIdx.x;
  const int p = tid >> 14, rem = tid & 16383;
  const int col = rem >> 7, k = rem & 127;
  w16[tid] = (f16)Ws[p][k*128 + col];
}

// ---------------- K1: LN + Q/K/V/Gate via MFMA ----------------
// 64 rows/block, 4 waves = 4 projections. zl[64][128] f16 with 16B-granule
// XOR swizzle (granule ^= row&7): write 2-way free, b128 reads uniform.
__global__ __launch_bounds__(256, 2) void k1_ln_qkvg(
    const float* __restrict__ z, const float* __restrict__ lng, const float* __restrict__ lnb,
    const f16* __restrict__ w16,
    const float* __restrict__ bq, const float* __restrict__ bk,
    const float* __restrict__ bv, const float* __restrict__ bg,
    f16* __restrict__ qb, f16* __restrict__ kbuf,
    f16* __restrict__ vbuf, f16* __restrict__ gateb)
{
  __shared__ f16 zl[64*128];   // 16 KB
  const int t = threadIdx.x;
  const int w = t >> 6, lane = t & 63;
  const int m = lane & 15, g = lane >> 4;
  const int row0 = blockIdx.x * 64;

  { // LayerNorm: 4 threads/row, 32 elems each -> swizzled f16 LDS
    const int r = t >> 2, part = t & 3;
    const float* zr = z + (size_t)(row0 + r)*DZC + part*32;
    float vals[32];
    float s = 0.f, sq = 0.f;
    #pragma unroll
    for (int i = 0; i < 8; ++i) {
      float4 v4 = reinterpret_cast<const float4*>(zr)[i];
      vals[i*4+0]=v4.x; vals[i*4+1]=v4.y; vals[i*4+2]=v4.z; vals[i*4+3]=v4.w;
      s  += v4.x+v4.y+v4.z+v4.w;
      sq += v4.x*v4.x + v4.y*v4.y + v4.z*v4.z + v4.w*v4.w;
    }
    s  += __shfl_xor(s, 1);  sq += __shfl_xor(sq, 1);
    s  += __shfl_xor(s, 2);  sq += __shfl_xor(sq, 2);
    const float mu  = s * (1.f/DZC);
    const float var = sq * (1.f/DZC) - mu*mu;
    const float rstd = rsqrtf(var + 1e-5f);
    const float* gg = lng + part*32;
    const float* bb = lnb + part*32;
    #pragma unroll
    for (int i = 0; i < 4; ++i) {
      f16x8 o;
      #pragma unroll
      for (int e = 0; e < 8; ++e)
        o[e] = (f16)((vals[i*8+e]-mu)*rstd*gg[i*8+e] + bb[i*8+e]);
      *reinterpret_cast<f16x8*>(zl + r*128 + (((part*4+i) ^ (r&7))*8)) = o;
    }
  }
  __syncthreads();

  const f16* wp = w16 + w*16384;
  f32x4 acc[4][8];
  #pragma unroll
  for (int it=0;it<4;++it)
    #pragma unroll
    for (int jt=0;jt<8;++jt) acc[it][jt] = (f32x4){0.f,0.f,0.f,0.f};

  #pragma unroll
  for (int ks = 0; ks < 4; ++ks) {
    f16x8 af[8];
    #pragma unroll
    for (int jt=0;jt<8;++jt)
      af[jt] = *reinterpret_cast<const f16x8*>(wp + (jt*16+m)*128 + ks*32 + g*8);
    f16x8 bf[4];
    #pragma unroll
    for (int it=0;it<4;++it)
      bf[it] = *reinterpret_cast<const f16x8*>(zl + (it*16+m)*128 + (((ks*4+g) ^ (m&7))*8));
    #pragma unroll
    for (int it=0;it<4;++it)
      #pragma unroll
      for (int jt=0;jt<8;++jt)
        acc[it][jt] = __builtin_amdgcn_mfma_f32_16x16x32_f16(af[jt], bf[it], acc[it][jt], 0,0,0);
  }

  const float* bsp = (w==0) ? bq : (w==1) ? bk : (w==2) ? bv : bg;
  float4 bias[8];
  #pragma unroll
  for (int jt=0;jt<8;++jt)
    bias[jt] = *reinterpret_cast<const float4*>(bsp + jt*16 + g*4);

  const int l = row0 >> 8, i0 = row0 & 255;
  if (w < 3) {
    f16* ob = (w==0) ? qb : (w==1) ? kbuf : vbuf;
    #pragma unroll
    for (int it=0;it<4;++it) {
      const int i = i0 + it*16 + m;
      #pragma unroll
      for (int jt=0;jt<8;++jt) {
        const int hh = jt >> 1, dh0 = (jt&1)*16 + g*4;
        f16x4 o;
        #pragma unroll
        for (int r=0;r<4;++r) o[r] = (f16)(acc[it][jt][r] + ((const float*)&bias[jt])[r]);
        *reinterpret_cast<f16x4*>(ob + ((size_t)(l*HN + hh)*NDIM + i)*DHD + dh0) = o;
      }
    }
  } else {
    #pragma unroll
    for (int it=0;it<4;++it) {
      const int rowg = row0 + it*16 + m;
      #pragma unroll
      for (int jt=0;jt<8;++jt) {
        f16x4 o;
        #pragma unroll
        for (int r=0;r<4;++r) {
          const float v = acc[it][jt][r] + ((const float*)&bias[jt])[r];
          o[r] = (f16)(1.f/(1.f + __expf(-v)));
        }
        *reinterpret_cast<f16x4*>(gateb + (size_t)rowg*DCC + jt*16 + g*4) = o;
      }
    }
  }
}

// ---------------- K2: MFMA fused attention per (l, h) ----------------
// Swapped-QK layout; coef inline from dist; per-it 16x64 P buffer (2KB/wave),
// all LDS granule-XOR-swizzled. LDS 24KB -> 4 blocks/CU @ 4 waves.
__global__ __launch_bounds__(256, 4) void k2_attn(
    const f16* __restrict__ qb, const f16* __restrict__ kbuf,
    const f16* __restrict__ vbuf, const float* __restrict__ dist,
    f16* __restrict__ zcom)
{
  __shared__ f16 vt[32*256];    // 16 KB swizzled V^T
  __shared__ f16 pl[4*16*64];   // 8 KB, wave-private 16x64
  const int t = threadIdx.x;
  const int w = t >> 6, lane = t & 63;
  const int m = lane & 15, g = lane >> 4;
  const int orig = blockIdx.x;
  const int swz = (orig & 7)*128 + (orig >> 3);   // bijective XCD swizzle
  const int l = swz >> 2, h = swz & 3;
  const size_t hb = (size_t)(l*HN + h) * (NDIM*DHD);

  { // build VT[c][j] = V[j][c], granule ^= c&7
    const f16x8* vg = reinterpret_cast<const f16x8*>(vbuf + hb + (size_t)t*DHD);
    #pragma unroll
    for (int p = 0; p < 4; ++p) {
      f16x8 v = vg[p];
      #pragma unroll
      for (int e = 0; e < 8; ++e) {
        const int c = p*8 + e;
        vt[c*256 + (((t>>3) ^ (c&7))*8) + (t&7)] = v[e];
      }
    }
  }

  f16x8 aq[4];
  #pragma unroll
  for (int it = 0; it < 4; ++it)
    aq[it] = *reinterpret_cast<const f16x8*>(qb + hb + (size_t)(w*64 + it*16 + m)*DHD + g*8);

  f32x4 o[4][2];
  float rs[4];
  #pragma unroll
  for (int it = 0; it < 4; ++it) {
    o[it][0] = (f32x4){0.f,0.f,0.f,0.f};
    o[it][1] = (f32x4){0.f,0.f,0.f,0.f};
    rs[it] = 0.f;
  }

  __syncthreads();

  const float* drow = dist + (size_t)l*(NDIM*NDIM);
  f16* plw = pl + w*1024;

  for (int jc = 0; jc < 4; ++jc) {
    f16x8 kf[4];
    #pragma unroll
    for (int jt = 0; jt < 4; ++jt)
      kf[jt] = *reinterpret_cast<const f16x8*>(kbuf + hb + (size_t)(jc*64 + jt*16 + m)*DHD + g*8);
    f16x8 bv[2][2];
    #pragma unroll
    for (int kc = 0; kc < 2; ++kc)
      #pragma unroll
      for (int ct = 0; ct < 2; ++ct)
        bv[kc][ct] = *reinterpret_cast<const f16x8*>(
            vt + (ct*16+m)*256 + (((jc*8 + kc*4 + g) ^ (m&7))*8));

    #pragma unroll
    for (int it = 0; it < 4; ++it) {
      f32x4 s[4];
      #pragma unroll
      for (int jt = 0; jt < 4; ++jt)
        s[jt] = __builtin_amdgcn_mfma_f32_16x16x32_f16(
            kf[jt], aq[it], (f32x4){0.f,0.f,0.f,0.f}, 0, 0, 0);

      const int i = w*64 + it*16 + m;
      #pragma unroll
      for (int jt = 0; jt < 4; ++jt) {
        const float4 dv = *reinterpret_cast<const float4*>(
            drow + (size_t)i*NDIM + jc*64 + jt*16 + g*4);
        const float dvr[4] = {dv.x, dv.y, dv.z, dv.w};
        f16x4 pk;
        float psum = 0.f;
        #pragma unroll
        for (int r = 0; r < 4; ++r) {
          const float cf = SCAL * __expf(dvr[r]*dvr[r]*(-1.f/128.f));
          const float p = __expf(s[jt][r] * cf);   // no-max softmax: logits tiny
          psum += p;
          pk[r] = (f16)p;
        }
        rs[it] += psum;
        *reinterpret_cast<f16x4*>(
            plw + m*64 + (((2*jt + (g>>1)) ^ (m&7))*8) + (g&1)*4) = pk;
      }
      __builtin_amdgcn_sched_barrier(0);

      #pragma unroll
      for (int kc = 0; kc < 2; ++kc) {
        f16x8 ap = *reinterpret_cast<const f16x8*>(
            plw + m*64 + (((4*kc + g) ^ (m&7))*8));
        o[it][0] = __builtin_amdgcn_mfma_f32_16x16x32_f16(ap, bv[kc][0], o[it][0], 0, 0, 0);
        o[it][1] = __builtin_amdgcn_mfma_f32_16x16x32_f16(ap, bv[kc][1], o[it][1], 0, 0, 0);
      }
      __builtin_amdgcn_sched_barrier(0);
    }
  }

  float rinv[4];
  #pragma unroll
  for (int it = 0; it < 4; ++it) {
    float v = rs[it];
    v += __shfl_xor(v, 16);
    v += __shfl_xor(v, 32);
    rinv[it] = 1.f / v;
  }

  // epilogue: normalize + store (gate applied in k3)
  #pragma unroll
  for (int it = 0; it < 4; ++it)
    #pragma unroll
    for (int r = 0; r < 4; ++r) {
      const float rr = __shfl(rinv[it], (lane & 48) + g*4 + r);
      const int row = l*NDIM + w*64 + it*16 + g*4 + r;
      #pragma unroll
      for (int ct = 0; ct < 2; ++ct) {
        const int col = h*DHD + ct*16 + m;
        zcom[(size_t)row*DCC + col] = (f16)(o[it][ct][r] * rr);
      }
    }
}

// ---------------- K3: gated output projection via MFMA ----------------
// 64 rows/block (1024 blocks), no LDS. B-frag = zcom * gate (v_pk_mul_f16).
__global__ __launch_bounds__(256, 4) void k3_out(
    const f16* __restrict__ zcom, const f16* __restrict__ gateb,
    const f16* __restrict__ wo16, const float* __restrict__ bo,
    float* __restrict__ out)
{
  const int t = threadIdx.x;
  const int w = t >> 6, lane = t & 63;
  const int m = lane & 15, g = lane >> 4;
  const size_t row = blockIdx.x*64 + w*16 + m;

  f32x4 acc[8];
  #pragma unroll
  for (int jt=0;jt<8;++jt) acc[jt] = (f32x4){0.f,0.f,0.f,0.f};

  #pragma unroll
  for (int ks = 0; ks < 4; ++ks) {
    f16x8 af[8];
    #pragma unroll
    for (int jt=0;jt<8;++jt)
      af[jt] = *reinterpret_cast<const f16x8*>(wo16 + (jt*16+m)*128 + ks*32 + g*8);
    f16x8 bf = *reinterpret_cast<const f16x8*>(zcom  + row*DCC + ks*32 + g*8);
    f16x8 gf = *reinterpret_cast<const f16x8*>(gateb + row*DCC + ks*32 + g*8);
    bf = bf * gf;
    #pragma unroll
    for (int jt=0;jt<8;++jt)
      acc[jt] = __builtin_amdgcn_mfma_f32_16x16x32_f16(af[jt], bf, acc[jt], 0,0,0);
  }

  #pragma unroll
  for (int jt=0;jt<8;++jt) {
    const float4 bias = *reinterpret_cast<const float4*>(bo + jt*16 + g*4);
    float4 o;
    o.x = acc[jt][0] + bias.x;
    o.y = acc[jt][1] + bias.y;
    o.z = acc[jt][2] + bias.z;
    o.w = acc[jt][3] + bias.w;
    *reinterpret_cast<float4*>(out + row*DZC + jt*16 + g*4) = o;
  }
}

extern "C" void kernel_launch(void* const* d_in, const int* in_sizes, int n_in,
                              void* d_out, int out_size, void* d_ws, size_t ws_size,
                              hipStream_t stream) {
  const float* z    = (const float*)d_in[0];
  const float* dist = (const float*)d_in[1];
  const float* lng  = (const float*)d_in[2];
  const float* lnb  = (const float*)d_in[3];
  const float* Wq   = (const float*)d_in[4];
  const float* bq   = (const float*)d_in[5];
  const float* Wk   = (const float*)d_in[6];
  const float* bk   = (const float*)d_in[7];
  const float* Wv   = (const float*)d_in[8];
  const float* bv   = (const float*)d_in[9];
  const float* Wg   = (const float*)d_in[10];
  const float* bg   = (const float*)d_in[11];
  const float* Wo   = (const float*)d_in[12];
  const float* bo   = (const float*)d_in[13];
  float* out = (float*)d_out;

  const size_t elems = (size_t)MROWS * DCC;  // 8,388,608
  f16* qb    = (f16*)d_ws;
  f16* kbuf  = qb    + elems;
  f16* vbuf  = kbuf  + elems;
  f16* gateb = vbuf  + elems;
  f16* zcom  = gateb + elems;
  f16* w16   = zcom  + elems;   // 5*16384 halves; total ws ≈ 84 MB

  k0b_pack<<<320, 256, 0, stream>>>(Wq, Wk, Wv, Wg, Wo, w16);
  k1_ln_qkvg<<<MROWS/64, 256, 0, stream>>>(z, lng, lnb, w16, bq, bk, bv, bg,
                                           qb, kbuf, vbuf, gateb);
  k2_attn<<<LDIM*HN, 256, 0, stream>>>(qb, kbuf, vbuf, dist, zcom);
  k3_out<<<MROWS/64, 256, 0, stream>>>(zcom, gateb, w16 + 4*16384, bo, out);
}

// Round 6
// 121.313 us; speedup vs baseline: 1.2487x; 1.2487x over previous
//
#include <hip/hip_runtime.h>
#include <hip/hip_fp16.h>

#define LDIM 256
#define NDIM 256
#define DZC  128
#define HN   4
#define DHD  32
#define DCC  128
#define MROWS (LDIM*NDIM)

typedef _Float16 f16;
typedef _Float16 f16x4 __attribute__((ext_vector_type(4)));
typedef _Float16 f16x8 __attribute__((ext_vector_type(8)));
typedef float    f32x4 __attribute__((ext_vector_type(4)));

#define SCAL 0.17677669529663687f   // 1/sqrt(32)

// ---------------- K0b: pack W^T f16 — w16[p][col][k] = W_p[k][col] ----------------
__global__ __launch_bounds__(256) void k0b_pack(
    const float* __restrict__ Wq, const float* __restrict__ Wk,
    const float* __restrict__ Wv, const float* __restrict__ Wg,
    const float* __restrict__ Wo, f16* __restrict__ w16)
{
  const float* Ws[5] = {Wq, Wk, Wv, Wg, Wo};
  const int tid = blockIdx.x * 256 + threadIdx.x;
  const int p = tid >> 14, rem = tid & 16383;
  const int col = rem >> 7, k = rem & 127;
  w16[tid] = (f16)Ws[p][k*128 + col];
}

// ---------------- K1: LN + Q/K/V/Gate via MFMA ----------------
__global__ __launch_bounds__(256, 2) void k1_ln_qkvg(
    const float* __restrict__ z, const float* __restrict__ lng, const float* __restrict__ lnb,
    const f16* __restrict__ w16,
    const float* __restrict__ bq, const float* __restrict__ bk,
    const float* __restrict__ bv, const float* __restrict__ bg,
    f16* __restrict__ qb, f16* __restrict__ kbuf,
    f16* __restrict__ vbuf, f16* __restrict__ gateb)
{
  __shared__ f16 zl[64*128];   // 16 KB
  const int t = threadIdx.x;
  const int w = t >> 6, lane = t & 63;
  const int m = lane & 15, g = lane >> 4;
  const int row0 = blockIdx.x * 64;

  { // LayerNorm: 4 threads/row, 32 elems each -> swizzled f16 LDS
    const int r = t >> 2, part = t & 3;
    const float* zr = z + (size_t)(row0 + r)*DZC + part*32;
    float vals[32];
    float s = 0.f, sq = 0.f;
    #pragma unroll
    for (int i = 0; i < 8; ++i) {
      float4 v4 = reinterpret_cast<const float4*>(zr)[i];
      vals[i*4+0]=v4.x; vals[i*4+1]=v4.y; vals[i*4+2]=v4.z; vals[i*4+3]=v4.w;
      s  += v4.x+v4.y+v4.z+v4.w;
      sq += v4.x*v4.x + v4.y*v4.y + v4.z*v4.z + v4.w*v4.w;
    }
    s  += __shfl_xor(s, 1);  sq += __shfl_xor(sq, 1);
    s  += __shfl_xor(s, 2);  sq += __shfl_xor(sq, 2);
    const float mu  = s * (1.f/DZC);
    const float var = sq * (1.f/DZC) - mu*mu;
    const float rstd = rsqrtf(var + 1e-5f);
    const float* gg = lng + part*32;
    const float* bb = lnb + part*32;
    #pragma unroll
    for (int i = 0; i < 4; ++i) {
      f16x8 o;
      #pragma unroll
      for (int e = 0; e < 8; ++e)
        o[e] = (f16)((vals[i*8+e]-mu)*rstd*gg[i*8+e] + bb[i*8+e]);
      *reinterpret_cast<f16x8*>(zl + r*128 + (((part*4+i) ^ (r&7))*8)) = o;
    }
  }
  __syncthreads();

  const f16* wp = w16 + w*16384;
  f32x4 acc[4][8];
  #pragma unroll
  for (int it=0;it<4;++it)
    #pragma unroll
    for (int jt=0;jt<8;++jt) acc[it][jt] = (f32x4){0.f,0.f,0.f,0.f};

  #pragma unroll
  for (int ks = 0; ks < 4; ++ks) {
    f16x8 af[8];
    #pragma unroll
    for (int jt=0;jt<8;++jt)
      af[jt] = *reinterpret_cast<const f16x8*>(wp + (jt*16+m)*128 + ks*32 + g*8);
    f16x8 bf[4];
    #pragma unroll
    for (int it=0;it<4;++it)
      bf[it] = *reinterpret_cast<const f16x8*>(zl + (it*16+m)*128 + (((ks*4+g) ^ (m&7))*8));
    #pragma unroll
    for (int it=0;it<4;++it)
      #pragma unroll
      for (int jt=0;jt<8;++jt)
        acc[it][jt] = __builtin_amdgcn_mfma_f32_16x16x32_f16(af[jt], bf[it], acc[it][jt], 0,0,0);
  }

  const float* bsp = (w==0) ? bq : (w==1) ? bk : (w==2) ? bv : bg;
  float4 bias[8];
  #pragma unroll
  for (int jt=0;jt<8;++jt)
    bias[jt] = *reinterpret_cast<const float4*>(bsp + jt*16 + g*4);

  const int l = row0 >> 8, i0 = row0 & 255;
  if (w < 3) {
    f16* ob = (w==0) ? qb : (w==1) ? kbuf : vbuf;
    #pragma unroll
    for (int it=0;it<4;++it) {
      const int i = i0 + it*16 + m;
      #pragma unroll
      for (int jt=0;jt<8;++jt) {
        const int hh = jt >> 1, dh0 = (jt&1)*16 + g*4;
        f16x4 o;
        #pragma unroll
        for (int r=0;r<4;++r) o[r] = (f16)(acc[it][jt][r] + ((const float*)&bias[jt])[r]);
        *reinterpret_cast<f16x4*>(ob + ((size_t)(l*HN + hh)*NDIM + i)*DHD + dh0) = o;
      }
    }
  } else {
    #pragma unroll
    for (int it=0;it<4;++it) {
      const int rowg = row0 + it*16 + m;
      #pragma unroll
      for (int jt=0;jt<8;++jt) {
        f16x4 o;
        #pragma unroll
        for (int r=0;r<4;++r) {
          const float v = acc[it][jt][r] + ((const float*)&bias[jt])[r];
          o[r] = (f16)(1.f/(1.f + __expf(-v)));
        }
        *reinterpret_cast<f16x4*>(gateb + (size_t)rowg*DCC + jt*16 + g*4) = o;
      }
    }
  }
}

// ---------------- K2: MFMA fused attention per (l, h) ----------------
// Swapped-QK layout; coef inline from dist (loads hoisted above QK^T MFMAs so
// latency hides under matrix pipe); per-it 16x64 P buffer; no sched_barriers
// (compiler pipelines across it iterations). launch_bounds(256,2): no spill.
__global__ __launch_bounds__(256, 2) void k2_attn(
    const f16* __restrict__ qb, const f16* __restrict__ kbuf,
    const f16* __restrict__ vbuf, const float* __restrict__ dist,
    f16* __restrict__ zcom)
{
  __shared__ f16 vt[32*256];    // 16 KB swizzled V^T
  __shared__ f16 pl[4*16*64];   // 8 KB, wave-private 16x64
  const int t = threadIdx.x;
  const int w = t >> 6, lane = t & 63;
  const int m = lane & 15, g = lane >> 4;
  const int orig = blockIdx.x;
  const int swz = (orig & 7)*128 + (orig >> 3);   // bijective XCD swizzle
  const int l = swz >> 2, h = swz & 3;
  const size_t hb = (size_t)(l*HN + h) * (NDIM*DHD);

  { // build VT[c][j] = V[j][c], granule ^= c&7
    const f16x8* vg = reinterpret_cast<const f16x8*>(vbuf + hb + (size_t)t*DHD);
    #pragma unroll
    for (int p = 0; p < 4; ++p) {
      f16x8 v = vg[p];
      #pragma unroll
      for (int e = 0; e < 8; ++e) {
        const int c = p*8 + e;
        vt[c*256 + (((t>>3) ^ (c&7))*8) + (t&7)] = v[e];
      }
    }
  }

  f16x8 aq[4];
  #pragma unroll
  for (int it = 0; it < 4; ++it)
    aq[it] = *reinterpret_cast<const f16x8*>(qb + hb + (size_t)(w*64 + it*16 + m)*DHD + g*8);

  f32x4 o[4][2];
  float rs[4];
  #pragma unroll
  for (int it = 0; it < 4; ++it) {
    o[it][0] = (f32x4){0.f,0.f,0.f,0.f};
    o[it][1] = (f32x4){0.f,0.f,0.f,0.f};
    rs[it] = 0.f;
  }

  __syncthreads();

  const float* drow = dist + (size_t)l*(NDIM*NDIM);
  f16* plw = pl + w*1024;

  for (int jc = 0; jc < 4; ++jc) {
    f16x8 kf[4];
    #pragma unroll
    for (int jt = 0; jt < 4; ++jt)
      kf[jt] = *reinterpret_cast<const f16x8*>(kbuf + hb + (size_t)(jc*64 + jt*16 + m)*DHD + g*8);
    f16x8 bv[2][2];
    #pragma unroll
    for (int kc = 0; kc < 2; ++kc)
      #pragma unroll
      for (int ct = 0; ct < 2; ++ct)
        bv[kc][ct] = *reinterpret_cast<const f16x8*>(
            vt + (ct*16+m)*256 + (((jc*8 + kc*4 + g) ^ (m&7))*8));

    #pragma unroll
    for (int it = 0; it < 4; ++it) {
      const int i = w*64 + it*16 + m;
      // dist loads issued BEFORE the MFMAs: latency hides under matrix pipe
      float4 dv[4];
      #pragma unroll
      for (int jt = 0; jt < 4; ++jt)
        dv[jt] = *reinterpret_cast<const float4*>(
            drow + (size_t)i*NDIM + jc*64 + jt*16 + g*4);

      f32x4 s[4];
      #pragma unroll
      for (int jt = 0; jt < 4; ++jt)
        s[jt] = __builtin_amdgcn_mfma_f32_16x16x32_f16(
            kf[jt], aq[it], (f32x4){0.f,0.f,0.f,0.f}, 0, 0, 0);

      #pragma unroll
      for (int jt = 0; jt < 4; ++jt) {
        const float dvr[4] = {dv[jt].x, dv[jt].y, dv[jt].z, dv[jt].w};
        f16x4 pk;
        float psum = 0.f;
        #pragma unroll
        for (int r = 0; r < 4; ++r) {
          const float cf = SCAL * __expf(dvr[r]*dvr[r]*(-1.f/128.f));
          const float p = __expf(s[jt][r] * cf);   // no-max softmax: logits tiny
          psum += p;
          pk[r] = (f16)p;
        }
        rs[it] += psum;
        *reinterpret_cast<f16x4*>(
            plw + m*64 + (((2*jt + (g>>1)) ^ (m&7))*8) + (g&1)*4) = pk;
      }

      #pragma unroll
      for (int kc = 0; kc < 2; ++kc) {
        f16x8 ap = *reinterpret_cast<const f16x8*>(
            plw + m*64 + (((4*kc + g) ^ (m&7))*8));
        o[it][0] = __builtin_amdgcn_mfma_f32_16x16x32_f16(ap, bv[kc][0], o[it][0], 0, 0, 0);
        o[it][1] = __builtin_amdgcn_mfma_f32_16x16x32_f16(ap, bv[kc][1], o[it][1], 0, 0, 0);
      }
    }
  }

  float rinv[4];
  #pragma unroll
  for (int it = 0; it < 4; ++it) {
    float v = rs[it];
    v += __shfl_xor(v, 16);
    v += __shfl_xor(v, 32);
    rinv[it] = 1.f / v;
  }

  // epilogue: normalize + store (gate applied in k3)
  #pragma unroll
  for (int it = 0; it < 4; ++it)
    #pragma unroll
    for (int r = 0; r < 4; ++r) {
      const float rr = __shfl(rinv[it], (lane & 48) + g*4 + r);
      const int row = l*NDIM + w*64 + it*16 + g*4 + r;
      #pragma unroll
      for (int ct = 0; ct < 2; ++ct) {
        const int col = h*DHD + ct*16 + m;
        zcom[(size_t)row*DCC + col] = (f16)(o[it][ct][r] * rr);
      }
    }
}

// ---------------- K3: gated output projection via MFMA ----------------
__global__ __launch_bounds__(256, 4) void k3_out(
    const f16* __restrict__ zcom, const f16* __restrict__ gateb,
    const f16* __restrict__ wo16, const float* __restrict__ bo,
    float* __restrict__ out)
{
  const int t = threadIdx.x;
  const int w = t >> 6, lane = t & 63;
  const int m = lane & 15, g = lane >> 4;
  const size_t row = blockIdx.x*64 + w*16 + m;

  f32x4 acc[8];
  #pragma unroll
  for (int jt=0;jt<8;++jt) acc[jt] = (f32x4){0.f,0.f,0.f,0.f};

  #pragma unroll
  for (int ks = 0; ks < 4; ++ks) {
    f16x8 af[8];
    #pragma unroll
    for (int jt=0;jt<8;++jt)
      af[jt] = *reinterpret_cast<const f16x8*>(wo16 + (jt*16+m)*128 + ks*32 + g*8);
    f16x8 bf = *reinterpret_cast<const f16x8*>(zcom  + row*DCC + ks*32 + g*8);
    f16x8 gf = *reinterpret_cast<const f16x8*>(gateb + row*DCC + ks*32 + g*8);
    bf = bf * gf;
    #pragma unroll
    for (int jt=0;jt<8;++jt)
      acc[jt] = __builtin_amdgcn_mfma_f32_16x16x32_f16(af[jt], bf, acc[jt], 0,0,0);
  }

  #pragma unroll
  for (int jt=0;jt<8;++jt) {
    const float4 bias = *reinterpret_cast<const float4*>(bo + jt*16 + g*4);
    float4 o;
    o.x = acc[jt][0] + bias.x;
    o.y = acc[jt][1] + bias.y;
    o.z = acc[jt][2] + bias.z;
    o.w = acc[jt][3] + bias.w;
    *reinterpret_cast<float4*>(out + row*DZC + jt*16 + g*4) = o;
  }
}

extern "C" void kernel_launch(void* const* d_in, const int* in_sizes, int n_in,
                              void* d_out, int out_size, void* d_ws, size_t ws_size,
                              hipStream_t stream) {
  const float* z    = (const float*)d_in[0];
  const float* dist = (const float*)d_in[1];
  const float* lng  = (const float*)d_in[2];
  const float* lnb  = (const float*)d_in[3];
  const float* Wq   = (const float*)d_in[4];
  const float* bq   = (const float*)d_in[5];
  const float* Wk   = (const float*)d_in[6];
  const float* bk   = (const float*)d_in[7];
  const float* Wv   = (const float*)d_in[8];
  const float* bv   = (const float*)d_in[9];
  const float* Wg   = (const float*)d_in[10];
  const float* bg   = (const float*)d_in[11];
  const float* Wo   = (const float*)d_in[12];
  const float* bo   = (const float*)d_in[13];
  float* out = (float*)d_out;

  const size_t elems = (size_t)MROWS * DCC;  // 8,388,608
  f16* qb    = (f16*)d_ws;
  f16* kbuf  = qb    + elems;
  f16* vbuf  = kbuf  + elems;
  f16* gateb = vbuf  + elems;
  f16* zcom  = gateb + elems;
  f16* w16   = zcom  + elems;   // 5*16384 halves; total ws ≈ 84 MB

  k0b_pack<<<320, 256, 0, stream>>>(Wq, Wk, Wv, Wg, Wo, w16);
  k1_ln_qkvg<<<MROWS/64, 256, 0, stream>>>(z, lng, lnb, w16, bq, bk, bv, bg,
                                           qb, kbuf, vbuf, gateb);
  k2_attn<<<LDIM*HN, 256, 0, stream>>>(qb, kbuf, vbuf, dist, zcom);
  k3_out<<<MROWS/64, 256, 0, stream>>>(zcom, gateb, w16 + 4*16384, bo, out);
}

// Round 7
// 119.119 us; speedup vs baseline: 1.2717x; 1.0184x over previous
//
#include <hip/hip_runtime.h>
#include <hip/hip_fp16.h>

#define LDIM 256
#define NDIM 256
#define DZC  128
#define HN   4
#define DHD  32
#define DCC  128
#define MROWS (LDIM*NDIM)

typedef _Float16 f16;
typedef _Float16 f16x4 __attribute__((ext_vector_type(4)));
typedef _Float16 f16x8 __attribute__((ext_vector_type(8)));
typedef float    f32x4 __attribute__((ext_vector_type(4)));

#define SCAL 0.17677669529663687f   // 1/sqrt(32)

// ---------------- K0b: pack W^T f16 — w16[p][col][k] = W_p[k][col] ----------------
__global__ __launch_bounds__(256) void k0b_pack(
    const float* __restrict__ Wq, const float* __restrict__ Wk,
    const float* __restrict__ Wv, const float* __restrict__ Wg,
    const float* __restrict__ Wo, f16* __restrict__ w16)
{
  const float* Ws[5] = {Wq, Wk, Wv, Wg, Wo};
  const int tid = blockIdx.x * 256 + threadIdx.x;
  const int p = tid >> 14, rem = tid & 16383;
  const int col = rem >> 7, k = rem & 127;
  w16[tid] = (f16)Ws[p][k*128 + col];
}

// ---------------- K1: LN + Q/K/V/Gate via MFMA ----------------
__global__ __launch_bounds__(256, 2) void k1_ln_qkvg(
    const float* __restrict__ z, const float* __restrict__ lng, const float* __restrict__ lnb,
    const f16* __restrict__ w16,
    const float* __restrict__ bq, const float* __restrict__ bk,
    const float* __restrict__ bv, const float* __restrict__ bg,
    f16* __restrict__ qb, f16* __restrict__ kbuf,
    f16* __restrict__ vbuf, f16* __restrict__ gateb)
{
  __shared__ f16 zl[64*128];   // 16 KB
  const int t = threadIdx.x;
  const int w = t >> 6, lane = t & 63;
  const int m = lane & 15, g = lane >> 4;
  const int row0 = blockIdx.x * 64;

  { // LayerNorm: 4 threads/row, 32 elems each -> swizzled f16 LDS
    const int r = t >> 2, part = t & 3;
    const float* zr = z + (size_t)(row0 + r)*DZC + part*32;
    float vals[32];
    float s = 0.f, sq = 0.f;
    #pragma unroll
    for (int i = 0; i < 8; ++i) {
      float4 v4 = reinterpret_cast<const float4*>(zr)[i];
      vals[i*4+0]=v4.x; vals[i*4+1]=v4.y; vals[i*4+2]=v4.z; vals[i*4+3]=v4.w;
      s  += v4.x+v4.y+v4.z+v4.w;
      sq += v4.x*v4.x + v4.y*v4.y + v4.z*v4.z + v4.w*v4.w;
    }
    s  += __shfl_xor(s, 1);  sq += __shfl_xor(sq, 1);
    s  += __shfl_xor(s, 2);  sq += __shfl_xor(sq, 2);
    const float mu  = s * (1.f/DZC);
    const float var = sq * (1.f/DZC) - mu*mu;
    const float rstd = rsqrtf(var + 1e-5f);
    const float* gg = lng + part*32;
    const float* bb = lnb + part*32;
    #pragma unroll
    for (int i = 0; i < 4; ++i) {
      f16x8 o;
      #pragma unroll
      for (int e = 0; e < 8; ++e)
        o[e] = (f16)((vals[i*8+e]-mu)*rstd*gg[i*8+e] + bb[i*8+e]);
      *reinterpret_cast<f16x8*>(zl + r*128 + (((part*4+i) ^ (r&7))*8)) = o;
    }
  }
  __syncthreads();

  const f16* wp = w16 + w*16384;
  f32x4 acc[4][8];
  #pragma unroll
  for (int it=0;it<4;++it)
    #pragma unroll
    for (int jt=0;jt<8;++jt) acc[it][jt] = (f32x4){0.f,0.f,0.f,0.f};

  #pragma unroll
  for (int ks = 0; ks < 4; ++ks) {
    f16x8 af[8];
    #pragma unroll
    for (int jt=0;jt<8;++jt)
      af[jt] = *reinterpret_cast<const f16x8*>(wp + (jt*16+m)*128 + ks*32 + g*8);
    f16x8 bf[4];
    #pragma unroll
    for (int it=0;it<4;++it)
      bf[it] = *reinterpret_cast<const f16x8*>(zl + (it*16+m)*128 + (((ks*4+g) ^ (m&7))*8));
    #pragma unroll
    for (int it=0;it<4;++it)
      #pragma unroll
      for (int jt=0;jt<8;++jt)
        acc[it][jt] = __builtin_amdgcn_mfma_f32_16x16x32_f16(af[jt], bf[it], acc[it][jt], 0,0,0);
  }

  const float* bsp = (w==0) ? bq : (w==1) ? bk : (w==2) ? bv : bg;
  float4 bias[8];
  #pragma unroll
  for (int jt=0;jt<8;++jt)
    bias[jt] = *reinterpret_cast<const float4*>(bsp + jt*16 + g*4);

  const int l = row0 >> 8, i0 = row0 & 255;
  if (w < 3) {
    f16* ob = (w==0) ? qb : (w==1) ? kbuf : vbuf;
    #pragma unroll
    for (int it=0;it<4;++it) {
      const int i = i0 + it*16 + m;
      #pragma unroll
      for (int jt=0;jt<8;++jt) {
        const int hh = jt >> 1, dh0 = (jt&1)*16 + g*4;
        f16x4 o;
        #pragma unroll
        for (int r=0;r<4;++r) o[r] = (f16)(acc[it][jt][r] + ((const float*)&bias[jt])[r]);
        *reinterpret_cast<f16x4*>(ob + ((size_t)(l*HN + hh)*NDIM + i)*DHD + dh0) = o;
      }
    }
  } else {
    #pragma unroll
    for (int it=0;it<4;++it) {
      const int rowg = row0 + it*16 + m;
      #pragma unroll
      for (int jt=0;jt<8;++jt) {
        f16x4 o;
        #pragma unroll
        for (int r=0;r<4;++r) {
          const float v = acc[it][jt][r] + ((const float*)&bias[jt])[r];
          o[r] = (f16)(1.f/(1.f + __expf(-v)));
        }
        *reinterpret_cast<f16x4*>(gateb + (size_t)rowg*DCC + jt*16 + g*4) = o;
      }
    }
  }
}

// ---------------- K2: MFMA fused attention per (l, h), in-register P ----------------
// Swapped QK^T leaves lane (m,g) with P[i=m][j=jt*16+g*4+r]. PV uses a permuted
// k-slot mapping j(k) = (2kc+(k&7)>>2)*16 + (k>>3)*4 + (k&3) — valid since both
// A (P, lane-local reg pack) and B (V^T LDS, permuted read) use the same slots.
// No P LDS, no intra-loop barriers. vt granule-XOR swizzle: 2-way, full banks.
__global__ __launch_bounds__(256, 3) void k2_attn(
    const f16* __restrict__ qb, const f16* __restrict__ kbuf,
    const f16* __restrict__ vbuf, const float* __restrict__ dist,
    f16* __restrict__ zcom)
{
  __shared__ f16 vt[32*256];    // 16 KB swizzled V^T
  const int t = threadIdx.x;
  const int w = t >> 6, lane = t & 63;
  const int m = lane & 15, g = lane >> 4;
  const int orig = blockIdx.x;
  const int swz = (orig & 7)*128 + (orig >> 3);   // bijective XCD swizzle
  const int l = swz >> 2, h = swz & 3;
  const size_t hb = (size_t)(l*HN + h) * (NDIM*DHD);

  { // build VT: half (c, j) at c*256 + ((j>>2)^(c&15))*4 + (j&3)
    const f16x8* vg = reinterpret_cast<const f16x8*>(vbuf + hb + (size_t)t*DHD);
    #pragma unroll
    for (int p = 0; p < 4; ++p) {
      f16x8 v = vg[p];
      #pragma unroll
      for (int e = 0; e < 8; ++e) {
        const int c = p*8 + e;
        vt[c*256 + (((t>>2) ^ (c&15))*4) + (t&3)] = v[e];
      }
    }
  }

  f16x8 aq[4];
  #pragma unroll
  for (int it = 0; it < 4; ++it)
    aq[it] = *reinterpret_cast<const f16x8*>(qb + hb + (size_t)(w*64 + it*16 + m)*DHD + g*8);

  f32x4 o[4][2];
  float rs[4];
  #pragma unroll
  for (int it = 0; it < 4; ++it) {
    o[it][0] = (f32x4){0.f,0.f,0.f,0.f};
    o[it][1] = (f32x4){0.f,0.f,0.f,0.f};
    rs[it] = 0.f;
  }

  __syncthreads();

  const float* drow = dist + (size_t)l*(NDIM*NDIM);

  for (int jc = 0; jc < 4; ++jc) {
    f16x8 kf[4];
    #pragma unroll
    for (int jt = 0; jt < 4; ++jt)
      kf[jt] = *reinterpret_cast<const f16x8*>(kbuf + hb + (size_t)(jc*64 + jt*16 + m)*DHD + g*8);

    // V^T B-frags, permuted k-slot read: slot e -> granule jc*16 + (2kc+(e>>2))*4 + g
    f16x8 bvv[2][2];
    #pragma unroll
    for (int kc = 0; kc < 2; ++kc)
      #pragma unroll
      for (int ct = 0; ct < 2; ++ct) {
        const int c = ct*16 + m;
        const f16x4 lo = *reinterpret_cast<const f16x4*>(
            vt + c*256 + (((jc*16 + (2*kc+0)*4 + g) ^ m) * 4));
        const f16x4 hi = *reinterpret_cast<const f16x4*>(
            vt + c*256 + (((jc*16 + (2*kc+1)*4 + g) ^ m) * 4));
        f16x8 bb;
        #pragma unroll
        for (int e = 0; e < 4; ++e) { bb[e] = lo[e]; bb[4+e] = hi[e]; }
        bvv[kc][ct] = bb;
      }

    #pragma unroll
    for (int it = 0; it < 4; ++it) {
      const int i = w*64 + it*16 + m;
      // dist loads issued before the MFMAs: latency hides under matrix pipe
      float4 dv[4];
      #pragma unroll
      for (int jt = 0; jt < 4; ++jt)
        dv[jt] = *reinterpret_cast<const float4*>(
            drow + (size_t)i*NDIM + jc*64 + jt*16 + g*4);

      f32x4 s[4];
      #pragma unroll
      for (int jt = 0; jt < 4; ++jt)
        s[jt] = __builtin_amdgcn_mfma_f32_16x16x32_f16(
            kf[jt], aq[it], (f32x4){0.f,0.f,0.f,0.f}, 0, 0, 0);

      f16x4 pk[4];
      #pragma unroll
      for (int jt = 0; jt < 4; ++jt) {
        const float dvr[4] = {dv[jt].x, dv[jt].y, dv[jt].z, dv[jt].w};
        float psum = 0.f;
        #pragma unroll
        for (int r = 0; r < 4; ++r) {
          const float cf = SCAL * __expf(dvr[r]*dvr[r]*(-1.f/128.f));
          const float p = __expf(s[jt][r] * cf);   // no-max softmax: logits tiny
          psum += p;
          pk[jt][r] = (f16)p;
        }
        rs[it] += psum;
      }

      // A-frags: lane-local pack, slot e of kc -> pk[2kc + (e>>2)][e&3]
      #pragma unroll
      for (int kc = 0; kc < 2; ++kc) {
        f16x8 ap;
        #pragma unroll
        for (int e = 0; e < 4; ++e) { ap[e] = pk[2*kc][e]; ap[4+e] = pk[2*kc+1][e]; }
        o[it][0] = __builtin_amdgcn_mfma_f32_16x16x32_f16(ap, bvv[kc][0], o[it][0], 0, 0, 0);
        o[it][1] = __builtin_amdgcn_mfma_f32_16x16x32_f16(ap, bvv[kc][1], o[it][1], 0, 0, 0);
      }
    }
  }

  float rinv[4];
  #pragma unroll
  for (int it = 0; it < 4; ++it) {
    float v = rs[it];
    v += __shfl_xor(v, 16);
    v += __shfl_xor(v, 32);
    rinv[it] = 1.f / v;
  }

  // epilogue: normalize + store (gate applied in k3)
  #pragma unroll
  for (int it = 0; it < 4; ++it)
    #pragma unroll
    for (int r = 0; r < 4; ++r) {
      const float rr = __shfl(rinv[it], (lane & 48) + g*4 + r);
      const int row = l*NDIM + w*64 + it*16 + g*4 + r;
      #pragma unroll
      for (int ct = 0; ct < 2; ++ct) {
        const int col = h*DHD + ct*16 + m;
        zcom[(size_t)row*DCC + col] = (f16)(o[it][ct][r] * rr);
      }
    }
}

// ---------------- K3: gated output projection via MFMA ----------------
__global__ __launch_bounds__(256, 4) void k3_out(
    const f16* __restrict__ zcom, const f16* __restrict__ gateb,
    const f16* __restrict__ wo16, const float* __restrict__ bo,
    float* __restrict__ out)
{
  const int t = threadIdx.x;
  const int w = t >> 6, lane = t & 63;
  const int m = lane & 15, g = lane >> 4;
  const size_t row = blockIdx.x*64 + w*16 + m;

  f32x4 acc[8];
  #pragma unroll
  for (int jt=0;jt<8;++jt) acc[jt] = (f32x4){0.f,0.f,0.f,0.f};

  #pragma unroll
  for (int ks = 0; ks < 4; ++ks) {
    f16x8 af[8];
    #pragma unroll
    for (int jt=0;jt<8;++jt)
      af[jt] = *reinterpret_cast<const f16x8*>(wo16 + (jt*16+m)*128 + ks*32 + g*8);
    f16x8 bf = *reinterpret_cast<const f16x8*>(zcom  + row*DCC + ks*32 + g*8);
    f16x8 gf = *reinterpret_cast<const f16x8*>(gateb + row*DCC + ks*32 + g*8);
    bf = bf * gf;
    #pragma unroll
    for (int jt=0;jt<8;++jt)
      acc[jt] = __builtin_amdgcn_mfma_f32_16x16x32_f16(af[jt], bf, acc[jt], 0,0,0);
  }

  #pragma unroll
  for (int jt=0;jt<8;++jt) {
    const float4 bias = *reinterpret_cast<const float4*>(bo + jt*16 + g*4);
    float4 o;
    o.x = acc[jt][0] + bias.x;
    o.y = acc[jt][1] + bias.y;
    o.z = acc[jt][2] + bias.z;
    o.w = acc[jt][3] + bias.w;
    *reinterpret_cast<float4*>(out + row*DZC + jt*16 + g*4) = o;
  }
}

extern "C" void kernel_launch(void* const* d_in, const int* in_sizes, int n_in,
                              void* d_out, int out_size, void* d_ws, size_t ws_size,
                              hipStream_t stream) {
  const float* z    = (const float*)d_in[0];
  const float* dist = (const float*)d_in[1];
  const float* lng  = (const float*)d_in[2];
  const float* lnb  = (const float*)d_in[3];
  const float* Wq   = (const float*)d_in[4];
  const float* bq   = (const float*)d_in[5];
  const float* Wk   = (const float*)d_in[6];
  const float* bk   = (const float*)d_in[7];
  const float* Wv   = (const float*)d_in[8];
  const float* bv   = (const float*)d_in[9];
  const float* Wg   = (const float*)d_in[10];
  const float* bg   = (const float*)d_in[11];
  const float* Wo   = (const float*)d_in[12];
  const float* bo   = (const float*)d_in[13];
  float* out = (float*)d_out;

  const size_t elems = (size_t)MROWS * DCC;  // 8,388,608
  f16* qb    = (f16*)d_ws;
  f16* kbuf  = qb    + elems;
  f16* vbuf  = kbuf  + elems;
  f16* gateb = vbuf  + elems;
  f16* zcom  = gateb + elems;
  f16* w16   = zcom  + elems;   // 5*16384 halves; total ws ≈ 84 MB

  k0b_pack<<<320, 256, 0, stream>>>(Wq, Wk, Wv, Wg, Wo, w16);
  k1_ln_qkvg<<<MROWS/64, 256, 0, stream>>>(z, lng, lnb, w16, bq, bk, bv, bg,
                                           qb, kbuf, vbuf, gateb);
  k2_attn<<<LDIM*HN, 256, 0, stream>>>(qb, kbuf, vbuf, dist, zcom);
  k3_out<<<MROWS/64, 256, 0, stream>>>(zcom, gateb, w16 + 4*16384, bo, out);
}

// Round 8
// 118.909 us; speedup vs baseline: 1.2740x; 1.0018x over previous
//
#include <hip/hip_runtime.h>
#include <hip/hip_fp16.h>

#define LDIM 256
#define NDIM 256
#define DZC  128
#define HN   4
#define DHD  32
#define DCC  128
#define MROWS (LDIM*NDIM)

typedef _Float16 f16;
typedef _Float16 f16x4 __attribute__((ext_vector_type(4)));
typedef _Float16 f16x8 __attribute__((ext_vector_type(8)));
typedef float    f32x4 __attribute__((ext_vector_type(4)));

#define SCAL 0.17677669529663687f   // 1/sqrt(32)

// ---------------- K0b: pack W^T f16 — w16[p][col][k] = W_p[k][col] ----------------
__global__ __launch_bounds__(256) void k0b_pack(
    const float* __restrict__ Wq, const float* __restrict__ Wk,
    const float* __restrict__ Wv, const float* __restrict__ Wg,
    const float* __restrict__ Wo, f16* __restrict__ w16)
{
  const float* Ws[5] = {Wq, Wk, Wv, Wg, Wo};
  const int tid = blockIdx.x * 256 + threadIdx.x;
  const int p = tid >> 14, rem = tid & 16383;
  const int col = rem >> 7, k = rem & 127;
  w16[tid] = (f16)Ws[p][k*128 + col];
}

// ---------------- K1: LN + Q/K/V/Gate via MFMA ----------------
__global__ __launch_bounds__(256, 2) void k1_ln_qkvg(
    const float* __restrict__ z, const float* __restrict__ lng, const float* __restrict__ lnb,
    const f16* __restrict__ w16,
    const float* __restrict__ bq, const float* __restrict__ bk,
    const float* __restrict__ bv, const float* __restrict__ bg,
    f16* __restrict__ qb, f16* __restrict__ kbuf,
    f16* __restrict__ vbuf, f16* __restrict__ gateb)
{
  __shared__ f16 zl[64*128];   // 16 KB
  const int t = threadIdx.x;
  const int w = t >> 6, lane = t & 63;
  const int m = lane & 15, g = lane >> 4;
  const int row0 = blockIdx.x * 64;

  { // LayerNorm: 4 threads/row, 32 elems each -> swizzled f16 LDS
    const int r = t >> 2, part = t & 3;
    const float* zr = z + (size_t)(row0 + r)*DZC + part*32;
    float vals[32];
    float s = 0.f, sq = 0.f;
    #pragma unroll
    for (int i = 0; i < 8; ++i) {
      float4 v4 = reinterpret_cast<const float4*>(zr)[i];
      vals[i*4+0]=v4.x; vals[i*4+1]=v4.y; vals[i*4+2]=v4.z; vals[i*4+3]=v4.w;
      s  += v4.x+v4.y+v4.z+v4.w;
      sq += v4.x*v4.x + v4.y*v4.y + v4.z*v4.z + v4.w*v4.w;
    }
    s  += __shfl_xor(s, 1);  sq += __shfl_xor(sq, 1);
    s  += __shfl_xor(s, 2);  sq += __shfl_xor(sq, 2);
    const float mu  = s * (1.f/DZC);
    const float var = sq * (1.f/DZC) - mu*mu;
    const float rstd = rsqrtf(var + 1e-5f);
    const float* gg = lng + part*32;
    const float* bb = lnb + part*32;
    #pragma unroll
    for (int i = 0; i < 4; ++i) {
      f16x8 o;
      #pragma unroll
      for (int e = 0; e < 8; ++e)
        o[e] = (f16)((vals[i*8+e]-mu)*rstd*gg[i*8+e] + bb[i*8+e]);
      *reinterpret_cast<f16x8*>(zl + r*128 + (((part*4+i) ^ (r&7))*8)) = o;
    }
  }
  __syncthreads();

  const f16* wp = w16 + w*16384;
  f32x4 acc[4][8];
  #pragma unroll
  for (int it=0;it<4;++it)
    #pragma unroll
    for (int jt=0;jt<8;++jt) acc[it][jt] = (f32x4){0.f,0.f,0.f,0.f};

  #pragma unroll
  for (int ks = 0; ks < 4; ++ks) {
    f16x8 af[8];
    #pragma unroll
    for (int jt=0;jt<8;++jt)
      af[jt] = *reinterpret_cast<const f16x8*>(wp + (jt*16+m)*128 + ks*32 + g*8);
    f16x8 bf[4];
    #pragma unroll
    for (int it=0;it<4;++it)
      bf[it] = *reinterpret_cast<const f16x8*>(zl + (it*16+m)*128 + (((ks*4+g) ^ (m&7))*8));
    #pragma unroll
    for (int it=0;it<4;++it)
      #pragma unroll
      for (int jt=0;jt<8;++jt)
        acc[it][jt] = __builtin_amdgcn_mfma_f32_16x16x32_f16(af[jt], bf[it], acc[it][jt], 0,0,0);
  }

  const float* bsp = (w==0) ? bq : (w==1) ? bk : (w==2) ? bv : bg;
  float4 bias[8];
  #pragma unroll
  for (int jt=0;jt<8;++jt)
    bias[jt] = *reinterpret_cast<const float4*>(bsp + jt*16 + g*4);

  const int l = row0 >> 8, i0 = row0 & 255;
  if (w < 3) {
    f16* ob = (w==0) ? qb : (w==1) ? kbuf : vbuf;
    #pragma unroll
    for (int it=0;it<4;++it) {
      const int i = i0 + it*16 + m;
      #pragma unroll
      for (int jt=0;jt<8;++jt) {
        const int hh = jt >> 1, dh0 = (jt&1)*16 + g*4;
        f16x4 o;
        #pragma unroll
        for (int r=0;r<4;++r) o[r] = (f16)(acc[it][jt][r] + ((const float*)&bias[jt])[r]);
        *reinterpret_cast<f16x4*>(ob + ((size_t)(l*HN + hh)*NDIM + i)*DHD + dh0) = o;
      }
    }
  } else {
    #pragma unroll
    for (int it=0;it<4;++it) {
      const int rowg = row0 + it*16 + m;
      #pragma unroll
      for (int jt=0;jt<8;++jt) {
        f16x4 o;
        #pragma unroll
        for (int r=0;r<4;++r) {
          const float v = acc[it][jt][r] + ((const float*)&bias[jt])[r];
          o[r] = (f16)(1.f/(1.f + __expf(-v)));
        }
        *reinterpret_cast<f16x4*>(gateb + (size_t)rowg*DCC + jt*16 + g*4) = o;
      }
    }
  }
}

// ---------------- K2: MFMA fused attention per (l, h, half), in-register P ----------------
// Grid 2048: block = (l,h,half), each wave owns 32 query rows -> 8 blocks/CU
// resident (16KB LDS, ~100 VGPR), 2x TLP vs R6. dist loads batched per jc
// (8 float4 issued together). Math identical to R6.
__global__ __launch_bounds__(256, 4) void k2_attn(
    const f16* __restrict__ qb, const f16* __restrict__ kbuf,
    const f16* __restrict__ vbuf, const float* __restrict__ dist,
    f16* __restrict__ zcom)
{
  __shared__ f16 vt[32*256];    // 16 KB swizzled V^T
  const int t = threadIdx.x;
  const int w = t >> 6, lane = t & 63;
  const int m = lane & 15, g = lane >> 4;
  const int orig = blockIdx.x;
  const int swz = (orig & 7)*256 + (orig >> 3);   // bijective XCD swizzle (2048%8==0)
  const int l = swz >> 3, h = (swz >> 1) & 3, half = swz & 1;
  const size_t hb = (size_t)(l*HN + h) * (NDIM*DHD);
  const int r0 = half*128 + w*32;                 // wave's first query row

  { // build VT: half (c, j) at c*256 + ((j>>2)^(c&15))*4 + (j&3)
    const f16x8* vg = reinterpret_cast<const f16x8*>(vbuf + hb + (size_t)t*DHD);
    #pragma unroll
    for (int p = 0; p < 4; ++p) {
      f16x8 v = vg[p];
      #pragma unroll
      for (int e = 0; e < 8; ++e) {
        const int c = p*8 + e;
        vt[c*256 + (((t>>2) ^ (c&15))*4) + (t&3)] = v[e];
      }
    }
  }

  f16x8 aq[2];
  #pragma unroll
  for (int it = 0; it < 2; ++it)
    aq[it] = *reinterpret_cast<const f16x8*>(qb + hb + (size_t)(r0 + it*16 + m)*DHD + g*8);

  f32x4 o[2][2];
  float rs[2];
  #pragma unroll
  for (int it = 0; it < 2; ++it) {
    o[it][0] = (f32x4){0.f,0.f,0.f,0.f};
    o[it][1] = (f32x4){0.f,0.f,0.f,0.f};
    rs[it] = 0.f;
  }

  __syncthreads();

  const float* drow = dist + (size_t)l*(NDIM*NDIM);

  for (int jc = 0; jc < 4; ++jc) {
    f16x8 kf[4];
    #pragma unroll
    for (int jt = 0; jt < 4; ++jt)
      kf[jt] = *reinterpret_cast<const f16x8*>(kbuf + hb + (size_t)(jc*64 + jt*16 + m)*DHD + g*8);

    // batched dist loads for both its: 8 independent float4 -> deep MLP
    float4 dv[2][4];
    #pragma unroll
    for (int it = 0; it < 2; ++it)
      #pragma unroll
      for (int jt = 0; jt < 4; ++jt)
        dv[it][jt] = *reinterpret_cast<const float4*>(
            drow + (size_t)(r0 + it*16 + m)*NDIM + jc*64 + jt*16 + g*4);

    // V^T B-frags, permuted k-slot read
    f16x8 bvv[2][2];
    #pragma unroll
    for (int kc = 0; kc < 2; ++kc)
      #pragma unroll
      for (int ct = 0; ct < 2; ++ct) {
        const int c = ct*16 + m;
        const f16x4 lo = *reinterpret_cast<const f16x4*>(
            vt + c*256 + (((jc*16 + (2*kc+0)*4 + g) ^ m) * 4));
        const f16x4 hi = *reinterpret_cast<const f16x4*>(
            vt + c*256 + (((jc*16 + (2*kc+1)*4 + g) ^ m) * 4));
        f16x8 bb;
        #pragma unroll
        for (int e = 0; e < 4; ++e) { bb[e] = lo[e]; bb[4+e] = hi[e]; }
        bvv[kc][ct] = bb;
      }

    #pragma unroll
    for (int it = 0; it < 2; ++it) {
      f32x4 s[4];
      #pragma unroll
      for (int jt = 0; jt < 4; ++jt)
        s[jt] = __builtin_amdgcn_mfma_f32_16x16x32_f16(
            kf[jt], aq[it], (f32x4){0.f,0.f,0.f,0.f}, 0, 0, 0);

      f16x4 pk[4];
      #pragma unroll
      for (int jt = 0; jt < 4; ++jt) {
        const float dvr[4] = {dv[it][jt].x, dv[it][jt].y, dv[it][jt].z, dv[it][jt].w};
        float psum = 0.f;
        #pragma unroll
        for (int r = 0; r < 4; ++r) {
          const float cf = SCAL * __expf(dvr[r]*dvr[r]*(-1.f/128.f));
          const float p = __expf(s[jt][r] * cf);   // no-max softmax: logits tiny
          psum += p;
          pk[jt][r] = (f16)p;
        }
        rs[it] += psum;
      }

      #pragma unroll
      for (int kc = 0; kc < 2; ++kc) {
        f16x8 ap;
        #pragma unroll
        for (int e = 0; e < 4; ++e) { ap[e] = pk[2*kc][e]; ap[4+e] = pk[2*kc+1][e]; }
        o[it][0] = __builtin_amdgcn_mfma_f32_16x16x32_f16(ap, bvv[kc][0], o[it][0], 0, 0, 0);
        o[it][1] = __builtin_amdgcn_mfma_f32_16x16x32_f16(ap, bvv[kc][1], o[it][1], 0, 0, 0);
      }
    }
  }

  float rinv[2];
  #pragma unroll
  for (int it = 0; it < 2; ++it) {
    float v = rs[it];
    v += __shfl_xor(v, 16);
    v += __shfl_xor(v, 32);
    rinv[it] = 1.f / v;
  }

  // epilogue: normalize + store (gate applied in k3)
  #pragma unroll
  for (int it = 0; it < 2; ++it)
    #pragma unroll
    for (int r = 0; r < 4; ++r) {
      const float rr = __shfl(rinv[it], (lane & 48) + g*4 + r);
      const int row = l*NDIM + r0 + it*16 + g*4 + r;
      #pragma unroll
      for (int ct = 0; ct < 2; ++ct) {
        const int col = h*DHD + ct*16 + m;
        zcom[(size_t)row*DCC + col] = (f16)(o[it][ct][r] * rr);
      }
    }
}

// ---------------- K3: gated output projection via MFMA ----------------
__global__ __launch_bounds__(256, 4) void k3_out(
    const f16* __restrict__ zcom, const f16* __restrict__ gateb,
    const f16* __restrict__ wo16, const float* __restrict__ bo,
    float* __restrict__ out)
{
  const int t = threadIdx.x;
  const int w = t >> 6, lane = t & 63;
  const int m = lane & 15, g = lane >> 4;
  const size_t row = blockIdx.x*64 + w*16 + m;

  f32x4 acc[8];
  #pragma unroll
  for (int jt=0;jt<8;++jt) acc[jt] = (f32x4){0.f,0.f,0.f,0.f};

  #pragma unroll
  for (int ks = 0; ks < 4; ++ks) {
    f16x8 af[8];
    #pragma unroll
    for (int jt=0;jt<8;++jt)
      af[jt] = *reinterpret_cast<const f16x8*>(wo16 + (jt*16+m)*128 + ks*32 + g*8);
    f16x8 bf = *reinterpret_cast<const f16x8*>(zcom  + row*DCC + ks*32 + g*8);
    f16x8 gf = *reinterpret_cast<const f16x8*>(gateb + row*DCC + ks*32 + g*8);
    bf = bf * gf;
    #pragma unroll
    for (int jt=0;jt<8;++jt)
      acc[jt] = __builtin_amdgcn_mfma_f32_16x16x32_f16(af[jt], bf, acc[jt], 0,0,0);
  }

  #pragma unroll
  for (int jt=0;jt<8;++jt) {
    const float4 bias = *reinterpret_cast<const float4*>(bo + jt*16 + g*4);
    float4 o;
    o.x = acc[jt][0] + bias.x;
    o.y = acc[jt][1] + bias.y;
    o.z = acc[jt][2] + bias.z;
    o.w = acc[jt][3] + bias.w;
    *reinterpret_cast<float4*>(out + row*DZC + jt*16 + g*4) = o;
  }
}

extern "C" void kernel_launch(void* const* d_in, const int* in_sizes, int n_in,
                              void* d_out, int out_size, void* d_ws, size_t ws_size,
                              hipStream_t stream) {
  const float* z    = (const float*)d_in[0];
  const float* dist = (const float*)d_in[1];
  const float* lng  = (const float*)d_in[2];
  const float* lnb  = (const float*)d_in[3];
  const float* Wq   = (const float*)d_in[4];
  const float* bq   = (const float*)d_in[5];
  const float* Wk   = (const float*)d_in[6];
  const float* bk   = (const float*)d_in[7];
  const float* Wv   = (const float*)d_in[8];
  const float* bv   = (const float*)d_in[9];
  const float* Wg   = (const float*)d_in[10];
  const float* bg   = (const float*)d_in[11];
  const float* Wo   = (const float*)d_in[12];
  const float* bo   = (const float*)d_in[13];
  float* out = (float*)d_out;

  const size_t elems = (size_t)MROWS * DCC;  // 8,388,608
  f16* qb    = (f16*)d_ws;
  f16* kbuf  = qb    + elems;
  f16* vbuf  = kbuf  + elems;
  f16* gateb = vbuf  + elems;
  f16* zcom  = gateb + elems;
  f16* w16   = zcom  + elems;   // 5*16384 halves; total ws ≈ 84 MB

  k0b_pack<<<320, 256, 0, stream>>>(Wq, Wk, Wv, Wg, Wo, w16);
  k1_ln_qkvg<<<MROWS/64, 256, 0, stream>>>(z, lng, lnb, w16, bq, bk, bv, bg,
                                           qb, kbuf, vbuf, gateb);
  k2_attn<<<LDIM*HN*2, 256, 0, stream>>>(qb, kbuf, vbuf, dist, zcom);
  k3_out<<<MROWS/64, 256, 0, stream>>>(zcom, gateb, w16 + 4*16384, bo, out);
}